// Round 17
// baseline (280.004 us; speedup 1.0000x reference)
//
#include <hip/hip_runtime.h>
#include <hip/hip_bf16.h>
#include <stdint.h>

#define T_TOK 2048
#define DIM 1024
#define FDIM 2048
#define NEXP 8
#define NSLOT 4096

typedef short bf16x8 __attribute__((ext_vector_type(8)));
typedef unsigned short u16x8 __attribute__((ext_vector_type(8)));
typedef float f32x4 __attribute__((ext_vector_type(4)));

__device__ __forceinline__ unsigned short f2bf(float f) {
  union { float f; unsigned int u; } v; v.f = f;
  unsigned int r = v.u + 0x7FFFu + ((v.u >> 16) & 1u);
  return (unsigned short)(r >> 16);
}

__device__ __forceinline__ float bf2f(unsigned short x) {
  union { unsigned int u; float f; } v; v.u = ((unsigned int)x) << 16;
  return v.f;
}

__device__ __forceinline__ void gld_lds16(const void* g, void* l) {
  __builtin_amdgcn_global_load_lds(
      (const __attribute__((address_space(1))) unsigned int*)g,
      (__attribute__((address_space(3))) unsigned int*)l, 16, 0, 0);
}

// ---------------- Router: fp32 exact, one wave per token; also emits xb (bf16 x) ----------------
__global__ void router_kernel(const float* __restrict__ x, const float* __restrict__ rk,
                              int* __restrict__ counts, int* __restrict__ tok_e,
                              float* __restrict__ tok_w, unsigned short* __restrict__ xb) {
  int w = threadIdx.x >> 6, lane = threadIdx.x & 63;
  int t = blockIdx.x * 4 + w;
  float acc[NEXP];
#pragma unroll
  for (int e = 0; e < NEXP; ++e) acc[e] = 0.f;
  const float4* xr = (const float4*)(x + (size_t)t * DIM);
#pragma unroll
  for (int i = 0; i < 4; ++i) {
    float4 xv = xr[i * 64 + lane];
    uint2 pk;
    pk.x = ((unsigned)f2bf(xv.y) << 16) | f2bf(xv.x);
    pk.y = ((unsigned)f2bf(xv.w) << 16) | f2bf(xv.z);
    *(uint2*)(xb + (size_t)t * DIM + (i * 64 + lane) * 4) = pk;
    int d0 = (i * 64 + lane) * 4;
#pragma unroll
    for (int j = 0; j < 4; ++j) {
      const float4* rr = (const float4*)(rk + (size_t)(d0 + j) * NEXP);
      float4 r0 = rr[0], r1 = rr[1];
      float xs = (j == 0) ? xv.x : (j == 1) ? xv.y : (j == 2) ? xv.z : xv.w;
      acc[0] += xs * r0.x; acc[1] += xs * r0.y; acc[2] += xs * r0.z; acc[3] += xs * r0.w;
      acc[4] += xs * r1.x; acc[5] += xs * r1.y; acc[6] += xs * r1.z; acc[7] += xs * r1.w;
    }
  }
#pragma unroll
  for (int off = 32; off > 0; off >>= 1) {
#pragma unroll
    for (int e = 0; e < NEXP; ++e) acc[e] += __shfl_xor(acc[e], off, 64);
  }
  if (lane == 0) {
    float m = acc[0];
    for (int e = 1; e < NEXP; ++e) m = fmaxf(m, acc[e]);
    float p[NEXP], s = 0.f;
    for (int e = 0; e < NEXP; ++e) { p[e] = expf(acc[e] - m); s += p[e]; }
    float inv = 1.f / s;
    for (int e = 0; e < NEXP; ++e) p[e] *= inv;
    int i1 = 0;
    for (int e = 1; e < NEXP; ++e) if (p[e] > p[i1]) i1 = e;      // ties -> lowest idx
    int i2 = (i1 == 0) ? 1 : 0;
    for (int e = 0; e < NEXP; ++e) if (e != i1 && p[e] > p[i2]) i2 = e;
    // reference: softmax over the two top PROBABILITIES
    float e1 = expf(p[i1]), e2 = expf(p[i2]);
    float winv = 1.f / (e1 + e2);
    tok_e[t * 2] = i1; tok_e[t * 2 + 1] = i2;
    tok_w[t * 2] = e1 * winv; tok_w[t * 2 + 1] = e2 * winv;
    atomicAdd(&counts[i1], 1); atomicAdd(&counts[i2], 1);
  }
}

// ---------------- Assign: offsets computed inline from counts (no scan kernel) ----------------
__global__ void assign_kernel(const int* __restrict__ tok_e, const float* __restrict__ tok_w,
                              const int* __restrict__ counts, int* __restrict__ cursor,
                              int* __restrict__ slot_token, float* __restrict__ slot_weight,
                              int* __restrict__ tok_slot) {
  int t = blockIdx.x * 256 + threadIdx.x;
  if (t >= T_TOK) return;
#pragma unroll
  for (int k = 0; k < 2; ++k) {
    int e = tok_e[t * 2 + k];
    int off = 0;
#pragma unroll
    for (int j = 0; j < NEXP; ++j) off += (j < e) ? counts[j] : 0;  // predicated, no array
    int pos = atomicAdd(&cursor[e], 1);
    int slot = off + pos;
    slot_token[slot] = t;
    slot_weight[slot] = tok_w[t * 2 + k];
    tok_slot[t * 2 + k] = slot;
  }
}

// Uniform tile decode from counts: ys -> (e, mt, off, cnt). SALU loop, 8 iters.
__device__ __forceinline__ bool tile_decode(const int* counts, int ys, int& e, int& mt,
                                            int& off, int& cnt) {
  mt = ys; off = 0;
  for (e = 0; e < NEXP; ++e) {
    cnt = counts[e];
    int ntl = (cnt + 127) >> 7;
    if (mt < ntl) return true;
    mt -= ntl; off += cnt;
  }
  return false;
}

// ---------------- Pass A: fuse[slot][F] = silu(X@Wg) * (X@Wu) ----------------
// r17: NO transpose kernel. B (weights) consumed as fp32 directly from the
// original [E][D][F] layout via reg-staging: wave-coalesced scalar loads along
// f (contiguous), f2bf convert, ds_write_b64 to the XOR-swizzled LDS layout
// the fragment reads expect (chunk c stored at c^(frow&7)). T14 split: loads
// issued before compute(cur), converted+written after. A (xb, L2-resident)
// keeps gld_lds + source-permute swizzle, double-buffered.
__global__ __launch_bounds__(256) void gemm_gateup(
    const unsigned short* __restrict__ xb, const float* __restrict__ wgf,
    const float* __restrict__ wuf, const int* __restrict__ counts,
    const int* __restrict__ slot_token, unsigned short* __restrict__ fuse) {
  int e, mt, off, cnt;
  if (!tile_decode(counts, blockIdx.y, e, mt, off, cnt)) return;
  int nt = blockIdx.x;  // 32 tiles of 64 f-cols
  __shared__ unsigned short Al[2][128 * 64];
  __shared__ unsigned short Bgl[2][64 * 64];
  __shared__ unsigned short Bul[2][64 * 64];
  int tid = threadIdx.x, w = tid >> 6, lane = tid & 63;
  int csrc = ((lane & 7) ^ (lane >> 3)) * 8;  // A: swizzled source chunk (bf16 elems)
  unsigned aoff[4];
#pragma unroll
  for (int ii = 0; ii < 4; ++ii) {
    int r = (w * 4 + ii) * 8 + (lane >> 3);
    int row = mt * 128 + r;
    int tok = (row < cnt) ? slot_token[off + row] : 0;  // clamp: garbage rows computed, not written
    aoff[ii] = (unsigned)(tok * DIM + csrc);
  }
  // B staging geometry: thread -> f-row bf = tid>>2 (16 per wave, coalesced),
  // d-quad dsel = tid&3. Per K-step: 4 iters x 4 scalar loads (d = dsel*4+it*16+i).
  int bf = tid >> 2, dsel = tid & 3;
  const float* wg_base = wgf + (size_t)e * DIM * FDIM + (size_t)(nt * 64 + bf);
  const float* wu_base = wuf + (size_t)e * DIM * FDIM + (size_t)(nt * 64 + bf);
  f32x4 accg[4][2] = {};
  f32x4 accu[4][2] = {};
  int wr = (w >> 1) * 64, wc = (w & 1) * 32;
  int swz = (lane & 7) << 3;
  int kof0 = ((lane >> 4) * 8) ^ swz;        // kk=0 swizzled col offset
  int kof1 = (32 + (lane >> 4) * 8) ^ swz;   // kk=1

  float bgv[16], buv[16];
  auto loadB = [&](int k0) {
#pragma unroll
    for (int it = 0; it < 4; ++it) {
#pragma unroll
      for (int i = 0; i < 4; ++i) {
        int d = k0 + dsel * 4 + it * 16 + i;
        bgv[it * 4 + i] = wg_base[(size_t)d * FDIM];
        buv[it * 4 + i] = wu_base[(size_t)d * FDIM];
      }
    }
  };
  auto writeB = [&](int buf) {
#pragma unroll
    for (int it = 0; it < 4; ++it) {
      int dl = dsel * 4 + it * 16;
      int o16 = bf * 64 + (((dl >> 3) ^ (bf & 7)) * 8) + (dl & 7);
      uint2 g, u;
      g.x = ((unsigned)f2bf(bgv[it * 4 + 1]) << 16) | f2bf(bgv[it * 4 + 0]);
      g.y = ((unsigned)f2bf(bgv[it * 4 + 3]) << 16) | f2bf(bgv[it * 4 + 2]);
      u.x = ((unsigned)f2bf(buv[it * 4 + 1]) << 16) | f2bf(buv[it * 4 + 0]);
      u.y = ((unsigned)f2bf(buv[it * 4 + 3]) << 16) | f2bf(buv[it * 4 + 2]);
      *(uint2*)&Bgl[buf][o16] = g;
      *(uint2*)&Bul[buf][o16] = u;
    }
  };
  auto stage_A = [&](int buf, int k0) {
#pragma unroll
    for (int ii = 0; ii < 4; ++ii)
      gld_lds16(xb + aoff[ii] + k0, &Al[buf][(w * 4 + ii) * 512]);
  };
  auto compute = [&](int buf) {
#pragma unroll
    for (int kk = 0; kk < 2; ++kk) {
      int kof = kk ? kof1 : kof0;
      bf16x8 af[4], bg[2], bu[2];
#pragma unroll
      for (int q = 0; q < 4; ++q)
        af[q] = *(const bf16x8*)&Al[buf][(wr + q * 16 + (lane & 15)) * 64 + kof];
#pragma unroll
      for (int q = 0; q < 2; ++q) {
        bg[q] = *(const bf16x8*)&Bgl[buf][(wc + q * 16 + (lane & 15)) * 64 + kof];
        bu[q] = *(const bf16x8*)&Bul[buf][(wc + q * 16 + (lane & 15)) * 64 + kof];
      }
#pragma unroll
      for (int m4 = 0; m4 < 4; ++m4) {
#pragma unroll
        for (int n4 = 0; n4 < 2; ++n4) {
          accg[m4][n4] = __builtin_amdgcn_mfma_f32_16x16x32_bf16(af[m4], bg[n4], accg[m4][n4], 0, 0, 0);
          accu[m4][n4] = __builtin_amdgcn_mfma_f32_16x16x32_bf16(af[m4], bu[n4], accu[m4][n4], 0, 0, 0);
        }
      }
    }
  };

  // prologue: fill buf0
  loadB(0);
  stage_A(0, 0);
  writeB(0);  // compiler waits the loaded regs
  asm volatile("s_waitcnt vmcnt(0) lgkmcnt(0)" ::: "memory");
  __builtin_amdgcn_s_barrier();
  int cb = 0;
  for (int t = 0; t < 16; ++t) {
    if (t < 15) {
      loadB((t + 1) * 64);            // issue early: hides under compute
      stage_A(cb ^ 1, (t + 1) * 64);
    }
    __builtin_amdgcn_sched_barrier(0);  // pin issues above compute
    compute(cb);
    if (t < 15) writeB(cb ^ 1);         // write late (T14)
    __builtin_amdgcn_sched_barrier(0);
    asm volatile("s_waitcnt vmcnt(0) lgkmcnt(0)" ::: "memory");
    __builtin_amdgcn_s_barrier();
    cb ^= 1;
  }

#pragma unroll
  for (int m4 = 0; m4 < 4; ++m4) {
#pragma unroll
    for (int n4 = 0; n4 < 2; ++n4) {
      f32x4 g = accg[m4][n4], u = accu[m4][n4];
#pragma unroll
      for (int j = 0; j < 4; ++j) {
        int r = wr + m4 * 16 + (lane >> 4) * 4 + j;  // C layout: row=(lane>>4)*4+reg
        int row = mt * 128 + r;
        if (row < cnt) {
          float gv = g[j];
          float val = gv / (1.f + expf(-gv)) * u[j];
          int f = nt * 64 + wc + n4 * 16 + (lane & 15);  // col=lane&15
          fuse[(size_t)(off + row) * FDIM + f] = f2bf(val);
        }
      }
    }
  }
}

// ---------------- Pass B: part4[z][slot][D] = w_slot * (fuse[:, z*512:(z+1)*512] @ WdT) ----------------
// Same r17 structure: A=fuse bf16 gld_lds (dbuf), B=wd fp32 reg-staged+cvt.
// wd layout [E][F][D]: d contiguous -> lane=d coalesced, scalar loads along f.
__global__ __launch_bounds__(256) void gemm_down(
    const unsigned short* __restrict__ fuse, const float* __restrict__ wdf,
    const int* __restrict__ counts, const float* __restrict__ slot_weight,
    unsigned short* __restrict__ part4) {
  int e, mt, off, cnt;
  if (!tile_decode(counts, blockIdx.y, e, mt, off, cnt)) return;
  int nt = blockIdx.x;   // 8 tiles of 128 d-cols
  int z = blockIdx.z;    // split-K quarter
  int kbase = z * (FDIM / 4);
  __shared__ unsigned short Al[2][128 * 64];
  __shared__ unsigned short Bl[2][128 * 64];
  int tid = threadIdx.x, w = tid >> 6, lane = tid & 63;
  int csrc = ((lane & 7) ^ (lane >> 3)) * 8;
  unsigned aoff[4];
#pragma unroll
  for (int ii = 0; ii < 4; ++ii) {
    int r = (w * 4 + ii) * 8 + (lane >> 3);
    int row = mt * 128 + r;
    int grow = (row < cnt) ? (off + row) : off;  // clamp to valid memory
    aoff[ii] = (unsigned)(grow * FDIM + kbase + csrc);
  }
  // B staging: thread -> d-row bd = tid>>1 (32 per wave, coalesced), f-quad
  // fsel = tid&1. Per K-step: 8 iters x 4 scalar loads (f = fsel*4+it*8+i).
  int bd = tid >> 1, fsel = tid & 1;
  const float* wd_base = wdf + (size_t)e * FDIM * DIM + (size_t)(nt * 128 + bd);
  f32x4 acc[4][4] = {};
  int wr = (w >> 1) * 64, wc = (w & 1) * 64;
  int swz = (lane & 7) << 3;
  int kof0 = ((lane >> 4) * 8) ^ swz;
  int kof1 = (32 + (lane >> 4) * 8) ^ swz;

  float bv[32];
  auto loadB = [&](int k0) {
#pragma unroll
    for (int it = 0; it < 8; ++it) {
#pragma unroll
      for (int i = 0; i < 4; ++i) {
        int f = kbase + k0 + fsel * 4 + it * 8 + i;
        bv[it * 4 + i] = wd_base[(size_t)f * DIM];
      }
    }
  };
  auto writeB = [&](int buf) {
#pragma unroll
    for (int it = 0; it < 8; ++it) {
      int fl = fsel * 4 + it * 8;
      int o16 = bd * 64 + (((fl >> 3) ^ (bd & 7)) * 8) + (fl & 7);
      uint2 v;
      v.x = ((unsigned)f2bf(bv[it * 4 + 1]) << 16) | f2bf(bv[it * 4 + 0]);
      v.y = ((unsigned)f2bf(bv[it * 4 + 3]) << 16) | f2bf(bv[it * 4 + 2]);
      *(uint2*)&Bl[buf][o16] = v;
    }
  };
  auto stage_A = [&](int buf, int k0) {
#pragma unroll
    for (int ii = 0; ii < 4; ++ii)
      gld_lds16(fuse + aoff[ii] + k0, &Al[buf][(w * 4 + ii) * 512]);
  };
  auto compute = [&](int buf) {
#pragma unroll
    for (int kk = 0; kk < 2; ++kk) {
      int kof = kk ? kof1 : kof0;
      bf16x8 af[4], bfr[4];
#pragma unroll
      for (int q = 0; q < 4; ++q) {
        af[q] = *(const bf16x8*)&Al[buf][(wr + q * 16 + (lane & 15)) * 64 + kof];
        bfr[q] = *(const bf16x8*)&Bl[buf][(wc + q * 16 + (lane & 15)) * 64 + kof];
      }
#pragma unroll
      for (int m4 = 0; m4 < 4; ++m4) {
#pragma unroll
        for (int n4 = 0; n4 < 4; ++n4) {
          acc[m4][n4] = __builtin_amdgcn_mfma_f32_16x16x32_bf16(af[m4], bfr[n4], acc[m4][n4], 0, 0, 0);
        }
      }
    }
  };

  loadB(0);
  stage_A(0, 0);
  writeB(0);
  asm volatile("s_waitcnt vmcnt(0) lgkmcnt(0)" ::: "memory");
  __builtin_amdgcn_s_barrier();
  int cb = 0;
  for (int t = 0; t < 8; ++t) {
    if (t < 7) {
      loadB((t + 1) * 64);
      stage_A(cb ^ 1, (t + 1) * 64);
    }
    __builtin_amdgcn_sched_barrier(0);
    compute(cb);
    if (t < 7) writeB(cb ^ 1);
    __builtin_amdgcn_sched_barrier(0);
    asm volatile("s_waitcnt vmcnt(0) lgkmcnt(0)" ::: "memory");
    __builtin_amdgcn_s_barrier();
    cb ^= 1;
  }

#pragma unroll
  for (int m4 = 0; m4 < 4; ++m4) {
#pragma unroll
    for (int j = 0; j < 4; ++j) {
      int r = wr + m4 * 16 + (lane >> 4) * 4 + j;
      int row = mt * 128 + r;
      if (row < cnt) {
        float wgt = slot_weight[off + row];
#pragma unroll
        for (int n4 = 0; n4 < 4; ++n4) {
          int d = nt * 128 + wc + n4 * 16 + (lane & 15);
          part4[((size_t)z * NSLOT + off + row) * DIM + d] = f2bf(acc[m4][n4][j] * wgt);
        }
      }
    }
  }
}

// ---------------- Combine: out[t] = sum over {slot0,slot1} x {z=0..3} ----------------
__global__ void combine_kernel(const unsigned short* __restrict__ part4,
                               const int* __restrict__ tok_slot, float* __restrict__ out) {
  int i = blockIdx.x * 256 + threadIdx.x;  // T*D/8 threads
  int t = i >> 7;
  int c = i & 127;  // 8-elem chunk within the D=1024 row
  int s0 = tok_slot[t * 2], s1 = tok_slot[t * 2 + 1];
  const u16x8* base = (const u16x8*)part4;
  float o[8];
#pragma unroll
  for (int j = 0; j < 8; ++j) o[j] = 0.f;
#pragma unroll
  for (int z = 0; z < 4; ++z) {
    u16x8 a = base[((size_t)z * NSLOT + s0) * (DIM / 8) + c];
    u16x8 b = base[((size_t)z * NSLOT + s1) * (DIM / 8) + c];
#pragma unroll
    for (int j = 0; j < 8; ++j) o[j] += bf2f(a[j]) + bf2f(b[j]);
  }
  float4* dst = (float4*)(out + (size_t)t * DIM + c * 8);
  dst[0] = make_float4(o[0], o[1], o[2], o[3]);
  dst[1] = make_float4(o[4], o[5], o[6], o[7]);
}

extern "C" void kernel_launch(void* const* d_in, const int* in_sizes, int n_in,
                              void* d_out, int out_size, void* d_ws, size_t ws_size,
                              hipStream_t stream) {
  (void)in_sizes; (void)n_in; (void)out_size;
  const float* x    = (const float*)d_in[0];
  const float* rk   = (const float*)d_in[1];
  const float* wg_f = (const float*)d_in[2];
  const float* wu_f = (const float*)d_in[3];
  const float* wd_f = (const float*)d_in[4];
  float* out = (float*)d_out;

  char* ws = (char*)d_ws;
  size_t o_xb   = 0;
  size_t o_fuse = o_xb + (size_t)T_TOK * DIM * 2;
  size_t o_part = o_fuse + (size_t)NSLOT * FDIM * 2;
  size_t o_meta = o_part + (size_t)4 * NSLOT * DIM * 2;
  size_t o_counts = o_meta;
  size_t o_cursor = o_counts + 32;
  size_t o_tok_e  = o_cursor + 32;
  size_t o_tok_w  = o_tok_e + (size_t)T_TOK * 2 * 4;
  size_t o_tok_s  = o_tok_w + (size_t)T_TOK * 2 * 4;
  size_t o_st     = o_tok_s + (size_t)T_TOK * 2 * 4;
  size_t o_sw     = o_st + (size_t)NSLOT * 4;
  size_t need     = o_sw + (size_t)NSLOT * 4;
  if (ws_size < need) return;  // diagnostic: absmax will equal ~0.785 (zero output)

  unsigned short* xb    = (unsigned short*)(ws + o_xb);
  unsigned short* fuse  = (unsigned short*)(ws + o_fuse);
  unsigned short* part4 = (unsigned short*)(ws + o_part);
  int* counts          = (int*)(ws + o_counts);
  int* cursor          = (int*)(ws + o_cursor);
  int* tok_e           = (int*)(ws + o_tok_e);
  float* tok_w         = (float*)(ws + o_tok_w);
  int* tok_slot        = (int*)(ws + o_tok_s);
  int* slot_token      = (int*)(ws + o_st);
  float* slot_weight   = (float*)(ws + o_sw);

  hipMemsetAsync(ws + o_counts, 0, 64, stream);  // counts + cursor
  router_kernel<<<T_TOK / 4, 256, 0, stream>>>(x, rk, counts, tok_e, tok_w, xb);
  assign_kernel<<<T_TOK / 256, 256, 0, stream>>>(tok_e, tok_w, counts, cursor,
                                                 slot_token, slot_weight, tok_slot);
  gemm_gateup<<<dim3(FDIM / 64, 40, 1), 256, 0, stream>>>(xb, wg_f, wu_f, counts,
                                                          slot_token, fuse);
  gemm_down<<<dim3(DIM / 128, 40, 4), 256, 0, stream>>>(fuse, wd_f, counts,
                                                        slot_weight, part4);
  combine_kernel<<<(T_TOK * DIM / 8) / 256, 256, 0, stream>>>(part4, tok_slot, out);
}

// Round 18
// 241.452 us; speedup vs baseline: 1.1597x; 1.1597x over previous
//
#include <hip/hip_runtime.h>
#include <hip/hip_bf16.h>
#include <stdint.h>

#define T_TOK 2048
#define DIM 1024
#define FDIM 2048
#define NEXP 8
#define NSLOT 4096

typedef short bf16x8 __attribute__((ext_vector_type(8)));
typedef unsigned short u16x8 __attribute__((ext_vector_type(8)));
typedef float f32x4 __attribute__((ext_vector_type(4)));

__device__ __forceinline__ unsigned short f2bf(float f) {
  union { float f; unsigned int u; } v; v.f = f;
  unsigned int r = v.u + 0x7FFFu + ((v.u >> 16) & 1u);
  return (unsigned short)(r >> 16);
}

__device__ __forceinline__ float bf2f(unsigned short x) {
  union { unsigned int u; float f; } v; v.u = ((unsigned int)x) << 16;
  return v.f;
}

__device__ __forceinline__ void gld_lds16(const void* g, void* l) {
  __builtin_amdgcn_global_load_lds(
      (const __attribute__((address_space(1))) unsigned int*)g,
      (__attribute__((address_space(3))) unsigned int*)l, 16, 0, 0);
}

// ---------------- Router: fp32 exact, one wave per token; also emits xb (bf16 x) ----------------
__global__ void router_kernel(const float* __restrict__ x, const float* __restrict__ rk,
                              int* __restrict__ counts, int* __restrict__ tok_e,
                              float* __restrict__ tok_w, unsigned short* __restrict__ xb) {
  int w = threadIdx.x >> 6, lane = threadIdx.x & 63;
  int t = blockIdx.x * 4 + w;
  float acc[NEXP];
#pragma unroll
  for (int e = 0; e < NEXP; ++e) acc[e] = 0.f;
  const float4* xr = (const float4*)(x + (size_t)t * DIM);
#pragma unroll
  for (int i = 0; i < 4; ++i) {
    float4 xv = xr[i * 64 + lane];
    uint2 pk;
    pk.x = ((unsigned)f2bf(xv.y) << 16) | f2bf(xv.x);
    pk.y = ((unsigned)f2bf(xv.w) << 16) | f2bf(xv.z);
    *(uint2*)(xb + (size_t)t * DIM + (i * 64 + lane) * 4) = pk;
    int d0 = (i * 64 + lane) * 4;
#pragma unroll
    for (int j = 0; j < 4; ++j) {
      const float4* rr = (const float4*)(rk + (size_t)(d0 + j) * NEXP);
      float4 r0 = rr[0], r1 = rr[1];
      float xs = (j == 0) ? xv.x : (j == 1) ? xv.y : (j == 2) ? xv.z : xv.w;
      acc[0] += xs * r0.x; acc[1] += xs * r0.y; acc[2] += xs * r0.z; acc[3] += xs * r0.w;
      acc[4] += xs * r1.x; acc[5] += xs * r1.y; acc[6] += xs * r1.z; acc[7] += xs * r1.w;
    }
  }
#pragma unroll
  for (int off = 32; off > 0; off >>= 1) {
#pragma unroll
    for (int e = 0; e < NEXP; ++e) acc[e] += __shfl_xor(acc[e], off, 64);
  }
  if (lane == 0) {
    float m = acc[0];
    for (int e = 1; e < NEXP; ++e) m = fmaxf(m, acc[e]);
    float p[NEXP], s = 0.f;
    for (int e = 0; e < NEXP; ++e) { p[e] = expf(acc[e] - m); s += p[e]; }
    float inv = 1.f / s;
    for (int e = 0; e < NEXP; ++e) p[e] *= inv;
    int i1 = 0;
    for (int e = 1; e < NEXP; ++e) if (p[e] > p[i1]) i1 = e;      // ties -> lowest idx
    int i2 = (i1 == 0) ? 1 : 0;
    for (int e = 0; e < NEXP; ++e) if (e != i1 && p[e] > p[i2]) i2 = e;
    // reference: softmax over the two top PROBABILITIES
    float e1 = expf(p[i1]), e2 = expf(p[i2]);
    float winv = 1.f / (e1 + e2);
    tok_e[t * 2] = i1; tok_e[t * 2 + 1] = i2;
    tok_w[t * 2] = e1 * winv; tok_w[t * 2 + 1] = e2 * winv;
    atomicAdd(&counts[i1], 1); atomicAdd(&counts[i2], 1);
  }
}

// ---------------- Assign: offsets computed inline from counts (no scan kernel) ----------------
__global__ void assign_kernel(const int* __restrict__ tok_e, const float* __restrict__ tok_w,
                              const int* __restrict__ counts, int* __restrict__ cursor,
                              int* __restrict__ slot_token, float* __restrict__ slot_weight,
                              int* __restrict__ tok_slot) {
  int t = blockIdx.x * 256 + threadIdx.x;
  if (t >= T_TOK) return;
#pragma unroll
  for (int k = 0; k < 2; ++k) {
    int e = tok_e[t * 2 + k];
    int off = 0;
#pragma unroll
    for (int j = 0; j < NEXP; ++j) off += (j < e) ? counts[j] : 0;  // predicated, no array
    int pos = atomicAdd(&cursor[e], 1);
    int slot = off + pos;
    slot_token[slot] = t;
    slot_weight[slot] = tok_w[t * 2 + k];
    tok_slot[t * 2 + k] = slot;
  }
}

// ---------------- Transpose+cvt: fp32 [E][R][C] -> bf16 [E][C][R], single launch ----------------
// 128r x 32c tiles: write bursts 256B contiguous (16 lanes x uint4), read 128B.
__global__ void transpose_all(const float* __restrict__ wg_f, const float* __restrict__ wu_f,
                              const float* __restrict__ wd_f, unsigned short* __restrict__ wgt,
                              unsigned short* __restrict__ wut, unsigned short* __restrict__ wdt) {
  __shared__ float lds[32][129];
  int bid = blockIdx.x, e = blockIdx.y;
  const float* in;
  unsigned short* out;
  int R, C, rb, cb;
  if (bid < 1024) {
    in = (bid < 512) ? wg_f : wu_f;
    out = (bid < 512) ? wgt : wut;
    int id = bid & 511;        // 8 rb x 64 cb tiles (1024x2048)
    R = DIM; C = FDIM;
    cb = (id & 63) * 32; rb = (id >> 6) * 128;
  } else {
    in = wd_f; out = wdt;
    int id = bid - 1024;       // 16 rb x 32 cb tiles (2048x1024)
    R = FDIM; C = DIM;
    cb = (id & 31) * 32; rb = (id >> 5) * 128;
  }
  size_t base = (size_t)e * (size_t)R * (size_t)C;
  int tid = threadIdx.x;
  int c4 = (tid & 7) * 4, row = tid >> 3;   // row in [0,32) per iter
#pragma unroll
  for (int it = 0; it < 4; ++it) {
    int r = row + it * 32;
    float4 v = *(const float4*)(in + base + (size_t)(rb + r) * C + cb + c4);
    lds[c4 + 0][r] = v.x; lds[c4 + 1][r] = v.y;
    lds[c4 + 2][r] = v.z; lds[c4 + 3][r] = v.w;
  }
  __syncthreads();
  int r8 = (tid & 15) * 8, c = tid >> 4;    // c in [0,16) per iter
#pragma unroll
  for (int it = 0; it < 2; ++it) {
    int cc = c + it * 16;
    uint4 v;
    v.x = ((unsigned)f2bf(lds[cc][r8 + 1]) << 16) | f2bf(lds[cc][r8 + 0]);
    v.y = ((unsigned)f2bf(lds[cc][r8 + 3]) << 16) | f2bf(lds[cc][r8 + 2]);
    v.z = ((unsigned)f2bf(lds[cc][r8 + 5]) << 16) | f2bf(lds[cc][r8 + 4]);
    v.w = ((unsigned)f2bf(lds[cc][r8 + 7]) << 16) | f2bf(lds[cc][r8 + 6]);
    *(uint4*)(out + base + (size_t)(cb + cc) * R + rb + r8) = v;
  }
}

// Uniform tile decode from counts: ys -> (e, mt, off, cnt). SALU loop, 8 iters.
__device__ __forceinline__ bool tile_decode(const int* counts, int ys, int& e, int& mt,
                                            int& off, int& cnt) {
  mt = ys; off = 0;
  for (e = 0; e < NEXP; ++e) {
    cnt = counts[e];
    int ntl = (cnt + 127) >> 7;
    if (mt < ntl) return true;
    mt -= ntl; off += cnt;
  }
  return false;
}

// ---------------- Pass A: fuse[slot][F] = silu(X@Wg) * (X@Wu) ----------------
// Symmetric dbuf 2-phase (best measured 75-77us). Swizzle = verified r8 layout.
__global__ __launch_bounds__(256) void gemm_gateup(
    const unsigned short* __restrict__ xb, const unsigned short* __restrict__ wg,
    const unsigned short* __restrict__ wu, const int* __restrict__ counts,
    const int* __restrict__ slot_token, unsigned short* __restrict__ fuse) {
  int e, mt, off, cnt;
  if (!tile_decode(counts, blockIdx.y, e, mt, off, cnt)) return;
  int nt = blockIdx.x;  // 32 tiles of 64 f-cols
  __shared__ unsigned short Al[2][128 * 64];
  __shared__ unsigned short Bgl[2][64 * 64];
  __shared__ unsigned short Bul[2][64 * 64];
  int tid = threadIdx.x, w = tid >> 6, lane = tid & 63;
  int csrc = ((lane & 7) ^ (lane >> 3)) * 8;  // swizzled source chunk (bf16 elems)
  unsigned aoff[4];
  unsigned boff[2];
#pragma unroll
  for (int ii = 0; ii < 4; ++ii) {
    int r = (w * 4 + ii) * 8 + (lane >> 3);
    int row = mt * 128 + r;
    int tok = (row < cnt) ? slot_token[off + row] : 0;  // clamp: garbage rows computed, not written
    aoff[ii] = (unsigned)(tok * DIM + csrc);
  }
#pragma unroll
  for (int ii = 0; ii < 2; ++ii) {
    int r = (w * 2 + ii) * 8 + (lane >> 3);
    boff[ii] = (unsigned)((e * FDIM + nt * 64 + r) * DIM + csrc);
  }
  f32x4 accg[4][2] = {};
  f32x4 accu[4][2] = {};
  int wr = (w >> 1) * 64, wc = (w & 1) * 32;
  int swz = (lane & 7) << 3;
  int kof0 = ((lane >> 4) * 8) ^ swz;        // kk=0 swizzled col offset
  int kof1 = (32 + (lane >> 4) * 8) ^ swz;   // kk=1

  auto stage = [&](int buf, int k0) {
#pragma unroll
    for (int ii = 0; ii < 4; ++ii)
      gld_lds16(xb + aoff[ii] + k0, &Al[buf][(w * 4 + ii) * 512]);
#pragma unroll
    for (int ii = 0; ii < 2; ++ii) {
      gld_lds16(wg + boff[ii] + k0, &Bgl[buf][(w * 2 + ii) * 512]);
      gld_lds16(wu + boff[ii] + k0, &Bul[buf][(w * 2 + ii) * 512]);
    }
  };
  auto compute = [&](int buf) {
#pragma unroll
    for (int kk = 0; kk < 2; ++kk) {
      int kof = kk ? kof1 : kof0;
      bf16x8 af[4], bg[2], bu[2];
#pragma unroll
      for (int q = 0; q < 4; ++q)
        af[q] = *(const bf16x8*)&Al[buf][(wr + q * 16 + (lane & 15)) * 64 + kof];
#pragma unroll
      for (int q = 0; q < 2; ++q) {
        bg[q] = *(const bf16x8*)&Bgl[buf][(wc + q * 16 + (lane & 15)) * 64 + kof];
        bu[q] = *(const bf16x8*)&Bul[buf][(wc + q * 16 + (lane & 15)) * 64 + kof];
      }
#pragma unroll
      for (int m4 = 0; m4 < 4; ++m4) {
#pragma unroll
        for (int n4 = 0; n4 < 2; ++n4) {
          accg[m4][n4] = __builtin_amdgcn_mfma_f32_16x16x32_bf16(af[m4], bg[n4], accg[m4][n4], 0, 0, 0);
          accu[m4][n4] = __builtin_amdgcn_mfma_f32_16x16x32_bf16(af[m4], bu[n4], accu[m4][n4], 0, 0, 0);
        }
      }
    }
  };

  stage(0, 0);
  asm volatile("s_waitcnt vmcnt(0)" ::: "memory");
  __builtin_amdgcn_s_barrier();
  int cb = 0;
  for (int k0 = 0; k0 < DIM; k0 += 64) {
    if (k0 + 64 < DIM) stage(cb ^ 1, k0 + 64);
    __builtin_amdgcn_sched_barrier(0);   // stage issues first
    compute(cb);
    __builtin_amdgcn_sched_barrier(0);   // compute stays above the wait (rule #18)
    asm volatile("s_waitcnt vmcnt(0)" ::: "memory");  // next-tile stage landed
    __builtin_amdgcn_s_barrier();
    cb ^= 1;
  }

#pragma unroll
  for (int m4 = 0; m4 < 4; ++m4) {
#pragma unroll
    for (int n4 = 0; n4 < 2; ++n4) {
      f32x4 g = accg[m4][n4], u = accu[m4][n4];
#pragma unroll
      for (int j = 0; j < 4; ++j) {
        int r = wr + m4 * 16 + (lane >> 4) * 4 + j;  // C layout: row=(lane>>4)*4+reg
        int row = mt * 128 + r;
        if (row < cnt) {
          float gv = g[j];
          float val = gv / (1.f + expf(-gv)) * u[j];
          int f = nt * 64 + wc + n4 * 16 + (lane & 15);  // col=lane&15
          fuse[(size_t)(off + row) * FDIM + f] = f2bf(val);
        }
      }
    }
  }
}

// ---------------- Pass B: part4[z][slot][D] = w_slot * (fuse[:, z*512:(z+1)*512] @ WdT) ----------------
// Asymmetric dbuf: A=fuse (L2-resident) single, B=wd dbuf'd, counted vmcnt.
__global__ __launch_bounds__(256) void gemm_down(
    const unsigned short* __restrict__ fuse, const unsigned short* __restrict__ wd,
    const int* __restrict__ counts, const float* __restrict__ slot_weight,
    unsigned short* __restrict__ part4) {
  int e, mt, off, cnt;
  if (!tile_decode(counts, blockIdx.y, e, mt, off, cnt)) return;
  int nt = blockIdx.x;   // 8 tiles of 128 d-cols
  int z = blockIdx.z;    // split-K quarter
  int kbase = z * (FDIM / 4);
  __shared__ unsigned short Al[128 * 64];
  __shared__ unsigned short Bl[2][128 * 64];
  int tid = threadIdx.x, w = tid >> 6, lane = tid & 63;
  int csrc = ((lane & 7) ^ (lane >> 3)) * 8;
  unsigned aoff[4];
  unsigned boff[4];
#pragma unroll
  for (int ii = 0; ii < 4; ++ii) {
    int r = (w * 4 + ii) * 8 + (lane >> 3);
    int row = mt * 128 + r;
    int grow = (row < cnt) ? (off + row) : off;  // clamp to valid memory
    aoff[ii] = (unsigned)(grow * FDIM + kbase + csrc);
    boff[ii] = (unsigned)((e * DIM + nt * 128 + r) * FDIM + kbase + csrc);
  }
  f32x4 acc[4][4] = {};
  int wr = (w >> 1) * 64, wc = (w & 1) * 64;
  int swz = (lane & 7) << 3;
  int kof0 = ((lane >> 4) * 8) ^ swz;
  int kof1 = (32 + (lane >> 4) * 8) ^ swz;

  auto stage_A = [&](int k0) {
#pragma unroll
    for (int ii = 0; ii < 4; ++ii)
      gld_lds16(fuse + aoff[ii] + k0, &Al[(w * 4 + ii) * 512]);
  };
  auto stage_B = [&](int buf, int k0) {
#pragma unroll
    for (int ii = 0; ii < 4; ++ii)
      gld_lds16(wd + boff[ii] + k0, &Bl[buf][(w * 4 + ii) * 512]);
  };
  auto compute = [&](int buf) {
#pragma unroll
    for (int kk = 0; kk < 2; ++kk) {
      int kof = kk ? kof1 : kof0;
      bf16x8 af[4], bfr[4];
#pragma unroll
      for (int q = 0; q < 4; ++q) {
        af[q] = *(const bf16x8*)&Al[(wr + q * 16 + (lane & 15)) * 64 + kof];
        bfr[q] = *(const bf16x8*)&Bl[buf][(wc + q * 16 + (lane & 15)) * 64 + kof];
      }
#pragma unroll
      for (int m4 = 0; m4 < 4; ++m4) {
#pragma unroll
        for (int n4 = 0; n4 < 4; ++n4) {
          acc[m4][n4] = __builtin_amdgcn_mfma_f32_16x16x32_bf16(af[m4], bfr[n4], acc[m4][n4], 0, 0, 0);
        }
      }
    }
  };

  stage_B(0, 0);
  stage_A(0);
  asm volatile("s_waitcnt vmcnt(0)" ::: "memory");
  __builtin_amdgcn_s_barrier();
  int cb = 0;
  for (int t = 0; t < 8; ++t) {
    if (t < 7) {
      stage_B(cb ^ 1, (t + 1) * 64);
      __builtin_amdgcn_sched_barrier(0);
      asm volatile("s_waitcnt vmcnt(4)" ::: "memory");
    } else {
      asm volatile("s_waitcnt vmcnt(0)" ::: "memory");
    }
    __builtin_amdgcn_s_barrier();
    __builtin_amdgcn_sched_barrier(0);
    compute(cb);
    __builtin_amdgcn_sched_barrier(0);
    __builtin_amdgcn_s_barrier();
    if (t < 7) stage_A((t + 1) * 64);
    cb ^= 1;
  }

#pragma unroll
  for (int m4 = 0; m4 < 4; ++m4) {
#pragma unroll
    for (int j = 0; j < 4; ++j) {
      int r = wr + m4 * 16 + (lane >> 4) * 4 + j;
      int row = mt * 128 + r;
      if (row < cnt) {
        float wgt = slot_weight[off + row];
#pragma unroll
        for (int n4 = 0; n4 < 4; ++n4) {
          int d = nt * 128 + wc + n4 * 16 + (lane & 15);
          part4[((size_t)z * NSLOT + off + row) * DIM + d] = f2bf(acc[m4][n4][j] * wgt);
        }
      }
    }
  }
}

// ---------------- Combine: out[t] = sum over {slot0,slot1} x {z=0..3} ----------------
__global__ void combine_kernel(const unsigned short* __restrict__ part4,
                               const int* __restrict__ tok_slot, float* __restrict__ out) {
  int i = blockIdx.x * 256 + threadIdx.x;  // T*D/8 threads
  int t = i >> 7;
  int c = i & 127;  // 8-elem chunk within the D=1024 row
  int s0 = tok_slot[t * 2], s1 = tok_slot[t * 2 + 1];
  const u16x8* base = (const u16x8*)part4;
  float o[8];
#pragma unroll
  for (int j = 0; j < 8; ++j) o[j] = 0.f;
#pragma unroll
  for (int z = 0; z < 4; ++z) {
    u16x8 a = base[((size_t)z * NSLOT + s0) * (DIM / 8) + c];
    u16x8 b = base[((size_t)z * NSLOT + s1) * (DIM / 8) + c];
#pragma unroll
    for (int j = 0; j < 8; ++j) o[j] += bf2f(a[j]) + bf2f(b[j]);
  }
  float4* dst = (float4*)(out + (size_t)t * DIM + c * 8);
  dst[0] = make_float4(o[0], o[1], o[2], o[3]);
  dst[1] = make_float4(o[4], o[5], o[6], o[7]);
}

extern "C" void kernel_launch(void* const* d_in, const int* in_sizes, int n_in,
                              void* d_out, int out_size, void* d_ws, size_t ws_size,
                              hipStream_t stream) {
  (void)in_sizes; (void)n_in; (void)out_size;
  const float* x    = (const float*)d_in[0];
  const float* rk   = (const float*)d_in[1];
  const float* wg_f = (const float*)d_in[2];
  const float* wu_f = (const float*)d_in[3];
  const float* wd_f = (const float*)d_in[4];
  float* out = (float*)d_out;

  char* ws = (char*)d_ws;
  size_t o_xb   = 0;
  size_t o_wg   = o_xb + (size_t)T_TOK * DIM * 2;
  size_t o_wu   = o_wg + (size_t)NEXP * FDIM * DIM * 2;
  size_t o_wd   = o_wu + (size_t)NEXP * FDIM * DIM * 2;
  size_t o_fuse = o_wd + (size_t)NEXP * DIM * FDIM * 2;
  size_t o_meta = o_fuse + (size_t)NSLOT * FDIM * 2;
  size_t o_counts = o_meta;
  size_t o_cursor = o_counts + 32;
  size_t o_tok_e  = o_cursor + 32;
  size_t o_tok_w  = o_tok_e + (size_t)T_TOK * 2 * 4;
  size_t o_tok_s  = o_tok_w + (size_t)T_TOK * 2 * 4;
  size_t o_st     = o_tok_s + (size_t)T_TOK * 2 * 4;
  size_t o_sw     = o_st + (size_t)NSLOT * 4;
  size_t need     = o_sw + (size_t)NSLOT * 4;
  if (ws_size < need) return;  // diagnostic: absmax will equal ~0.785 (zero output)

  unsigned short* xb    = (unsigned short*)(ws + o_xb);
  unsigned short* wgt   = (unsigned short*)(ws + o_wg);
  unsigned short* wut   = (unsigned short*)(ws + o_wu);
  unsigned short* wdt   = (unsigned short*)(ws + o_wd);
  unsigned short* fuse  = (unsigned short*)(ws + o_fuse);
  // part4 (4 x NSLOT x DIM bf16 = 33.5MB) aliases wgt+wut (64MB): dead after
  // gemm_gateup; every call rewrites them in stream order -> deterministic.
  unsigned short* part4 = (unsigned short*)(ws + o_wg);
  int* counts          = (int*)(ws + o_counts);
  int* cursor          = (int*)(ws + o_cursor);
  int* tok_e           = (int*)(ws + o_tok_e);
  float* tok_w         = (float*)(ws + o_tok_w);
  int* tok_slot        = (int*)(ws + o_tok_s);
  int* slot_token      = (int*)(ws + o_st);
  float* slot_weight   = (float*)(ws + o_sw);

  hipMemsetAsync(ws + o_counts, 0, 64, stream);  // counts + cursor
  router_kernel<<<T_TOK / 4, 256, 0, stream>>>(x, rk, counts, tok_e, tok_w, xb);
  assign_kernel<<<T_TOK / 256, 256, 0, stream>>>(tok_e, tok_w, counts, cursor,
                                                 slot_token, slot_weight, tok_slot);
  transpose_all<<<dim3(1536, NEXP), 256, 0, stream>>>(wg_f, wu_f, wd_f, wgt, wut, wdt);
  gemm_gateup<<<dim3(FDIM / 64, 40, 1), 256, 0, stream>>>(xb, wgt, wut, counts,
                                                          slot_token, fuse);
  gemm_down<<<dim3(DIM / 128, 40, 4), 256, 0, stream>>>(fuse, wdt, counts,
                                                        slot_weight, part4);
  combine_kernel<<<(T_TOK * DIM / 8) / 256, 256, 0, stream>>>(part4, tok_slot, out);
}